// Round 8
// baseline (60.112 us; speedup 1.0000x reference)
//
#include <hip/hip_runtime.h>

#define DIM 64
#define MAX_REL 256
#define RPAD2 36             // padded LDS stride (floats) for a 32-float R half-row

typedef int          vint4   __attribute__((ext_vector_type(4)));
typedef unsigned int vuint2  __attribute__((ext_vector_type(2)));
typedef float        vfloat4 __attribute__((ext_vector_type(4)));

// ---------------- Kernel 1: per-row absmax + int8 quantize into 2 feature planes ----
// Plane p holds features [32p, 32p+32) of every row: [nrows][8 words] each.
__global__ void __launch_bounds__(256) quantize_rows_kernel(
        const float* __restrict__ X,      // [nrows, 64] fp32
        unsigned int* __restrict__ Xq,    // [2][nrows][8] words
        float* __restrict__ S,            // [nrows] scale = rowmax/127
        int nrows) {
    const int row = blockIdx.x * 32 + (threadIdx.x >> 3);
    if (row >= nrows) return;
    const int sub = threadIdx.x & 7;

    const float* xr = X + (size_t)row * DIM + sub * 8;
    const vfloat4 a = *reinterpret_cast<const vfloat4*>(xr);
    const vfloat4 b = *reinterpret_cast<const vfloat4*>(xr + 4);

    unsigned int m = __float_as_uint(a.x) & 0x7fffffffu;
    m = max(m, __float_as_uint(a.y) & 0x7fffffffu);
    m = max(m, __float_as_uint(a.z) & 0x7fffffffu);
    m = max(m, __float_as_uint(a.w) & 0x7fffffffu);
    m = max(m, __float_as_uint(b.x) & 0x7fffffffu);
    m = max(m, __float_as_uint(b.y) & 0x7fffffffu);
    m = max(m, __float_as_uint(b.z) & 0x7fffffffu);
    m = max(m, __float_as_uint(b.w) & 0x7fffffffu);
    m = max(m, (unsigned int)__shfl_xor((int)m, 1, 64));
    m = max(m, (unsigned int)__shfl_xor((int)m, 2, 64));
    m = max(m, (unsigned int)__shfl_xor((int)m, 4, 64));

    const float rowmax = __uint_as_float(m);
    const float inv = (rowmax > 0.0f) ? (127.0f / rowmax) : 0.0f;

    const int q0 = (int)rintf(a.x * inv), q1 = (int)rintf(a.y * inv);
    const int q2 = (int)rintf(a.z * inv), q3 = (int)rintf(a.w * inv);
    const int q4 = (int)rintf(b.x * inv), q5 = (int)rintf(b.y * inv);
    const int q6 = (int)rintf(b.z * inv), q7 = (int)rintf(b.w * inv);
    vuint2 o;
    o.x = (unsigned int)(q0 & 0xff) | ((unsigned int)(q1 & 0xff) << 8) |
          ((unsigned int)(q2 & 0xff) << 16) | ((unsigned int)(q3 & 0xff) << 24);
    o.y = (unsigned int)(q4 & 0xff) | ((unsigned int)(q5 & 0xff) << 8) |
          ((unsigned int)(q6 & 0xff) << 16) | ((unsigned int)(q7 & 0xff) << 24);

    // plane = sub>>2 (features 0-31 -> plane 0, 32-63 -> plane 1)
    unsigned int* dst = Xq + (size_t)(sub >> 2) * nrows * 8 + (size_t)row * 8 + (sub & 3) * 2;
    *reinterpret_cast<vuint2*>(dst) = o;

    if (sub == 0) S[row] = rowmax * (1.0f / 127.0f);
}

// ---------------- int8 dot helper (8 features) ----------------
__device__ __forceinline__ float dot8_i8(const vuint2& s, const vuint2& t,
                                         const vfloat4& ra, const vfloat4& rb) {
    float acc = 0.f;
    int p;
    p = ((int)(s.x << 24) >> 24) * ((int)(t.x << 24) >> 24); acc = fmaf((float)p, ra.x, acc);
    p = ((int)(s.x << 16) >> 24) * ((int)(t.x << 16) >> 24); acc = fmaf((float)p, ra.y, acc);
    p = ((int)(s.x <<  8) >> 24) * ((int)(t.x <<  8) >> 24); acc = fmaf((float)p, ra.z, acc);
    p = ((int)(s.x      ) >> 24) * ((int)(t.x      ) >> 24); acc = fmaf((float)p, ra.w, acc);
    p = ((int)(s.y << 24) >> 24) * ((int)(t.y << 24) >> 24); acc = fmaf((float)p, rb.x, acc);
    p = ((int)(s.y << 16) >> 24) * ((int)(t.y << 16) >> 24); acc = fmaf((float)p, rb.y, acc);
    p = ((int)(s.y <<  8) >> 24) * ((int)(t.y <<  8) >> 24); acc = fmaf((float)p, rb.z, acc);
    p = ((int)(s.y      ) >> 24) * ((int)(t.y      ) >> 24); acc = fmaf((float)p, rb.w, acc);
    return acc;
}

// ---------------- Phase kernel: 32 features, gather set fits one XCD L2 --------
// 4 lanes/edge, 4 edges/group, 128 groups per 512-thread block, persistent grid.
// PHASE 0: out = partial (unscaled). PHASE 1: out = (out + partial) * S[s]*S[t].
template<int PHASE>
__global__ void __launch_bounds__(512) distmult_i8_phase_kernel(
        const unsigned int* __restrict__ Xq,  // [2][nrows][8] words
        const float* __restrict__ R,          // [nrel, 64] fp32
        const float* __restrict__ S,          // [nrows]
        const int*   __restrict__ src,
        const int*   __restrict__ tgt,
        const int*   __restrict__ rel,
        float*       __restrict__ out,
        int num_edges, int nrows, int nrel) {
    __shared__ float Rs[MAX_REL * RPAD2];     // 36 KB -> 4 blocks/CU

    // stage this phase's R half (32 floats/row) into LDS
    for (int i = threadIdx.x; i < nrel * 8; i += 512) {
        const int r = i >> 3, c = (i & 7) * 4;
        *reinterpret_cast<vfloat4*>(&Rs[r * RPAD2 + c]) =
            *reinterpret_cast<const vfloat4*>(R + (size_t)r * DIM + PHASE * 32 + c);
    }
    __syncthreads();

    const unsigned int* Xp = Xq + (size_t)PHASE * nrows * 8;
    const int sub = threadIdx.x & 3;          // lane within 4-lane edge group
    const int w0  = sub * 2;                  // word offset in 8-word half-row
    const int f0  = sub * 8;                  // feature offset in LDS R half-row
    int g = blockIdx.x * 128 + (threadIdx.x >> 2);
    const int gstr = gridDim.x * 128;
    const int ngroups = (num_edges + 3) >> 2;

    for (; g < ngroups; g += gstr) {
        const int e0 = g << 2;
        if (e0 + 3 < num_edges) {
            const vint4 s4 = *reinterpret_cast<const vint4*>(src + e0);
            const vint4 t4 = *reinterpret_cast<const vint4*>(tgt + e0);
            const vint4 r4 = *reinterpret_cast<const vint4*>(rel + e0);

            const vuint2 sv0 = *reinterpret_cast<const vuint2*>(Xp + (size_t)s4.x * 8 + w0);
            const vuint2 sv1 = *reinterpret_cast<const vuint2*>(Xp + (size_t)s4.y * 8 + w0);
            const vuint2 sv2 = *reinterpret_cast<const vuint2*>(Xp + (size_t)s4.z * 8 + w0);
            const vuint2 sv3 = *reinterpret_cast<const vuint2*>(Xp + (size_t)s4.w * 8 + w0);
            const vuint2 tv0 = *reinterpret_cast<const vuint2*>(Xp + (size_t)t4.x * 8 + w0);
            const vuint2 tv1 = *reinterpret_cast<const vuint2*>(Xp + (size_t)t4.y * 8 + w0);
            const vuint2 tv2 = *reinterpret_cast<const vuint2*>(Xp + (size_t)t4.z * 8 + w0);
            const vuint2 tv3 = *reinterpret_cast<const vuint2*>(Xp + (size_t)t4.w * 8 + w0);

            const float* r0 = &Rs[r4.x * RPAD2 + f0];
            const float* r1 = &Rs[r4.y * RPAD2 + f0];
            const float* r2 = &Rs[r4.z * RPAD2 + f0];
            const float* r3 = &Rs[r4.w * RPAD2 + f0];

            float a0 = dot8_i8(sv0, tv0, *reinterpret_cast<const vfloat4*>(r0),
                                          *reinterpret_cast<const vfloat4*>(r0 + 4));
            float a1 = dot8_i8(sv1, tv1, *reinterpret_cast<const vfloat4*>(r1),
                                          *reinterpret_cast<const vfloat4*>(r1 + 4));
            float a2 = dot8_i8(sv2, tv2, *reinterpret_cast<const vfloat4*>(r2),
                                          *reinterpret_cast<const vfloat4*>(r2 + 4));
            float a3 = dot8_i8(sv3, tv3, *reinterpret_cast<const vfloat4*>(r3),
                                          *reinterpret_cast<const vfloat4*>(r3 + 4));

            // reduce across the 4-lane group
            a0 += __shfl_xor(a0, 1, 64); a1 += __shfl_xor(a1, 1, 64);
            a2 += __shfl_xor(a2, 1, 64); a3 += __shfl_xor(a3, 1, 64);
            a0 += __shfl_xor(a0, 2, 64); a1 += __shfl_xor(a1, 2, 64);
            a2 += __shfl_xor(a2, 2, 64); a3 += __shfl_xor(a3, 2, 64);

            if (sub == 0) {
                vfloat4 o;
                if (PHASE == 0) {
                    o.x = a0; o.y = a1; o.z = a2; o.w = a3;
                } else {
                    const float sc0 = S[s4.x] * S[t4.x];
                    const float sc1 = S[s4.y] * S[t4.y];
                    const float sc2 = S[s4.z] * S[t4.z];
                    const float sc3 = S[s4.w] * S[t4.w];
                    const vfloat4 prev = *reinterpret_cast<const vfloat4*>(out + e0);
                    o.x = (prev.x + a0) * sc0;
                    o.y = (prev.y + a1) * sc1;
                    o.z = (prev.z + a2) * sc2;
                    o.w = (prev.w + a3) * sc3;
                }
                *reinterpret_cast<vfloat4*>(out + e0) = o;
            }
        } else {
            for (int e = e0; e < num_edges; ++e) {
                const int s = src[e], t = tgt[e], r = rel[e];
                const vuint2 sv = *reinterpret_cast<const vuint2*>(Xp + (size_t)s * 8 + w0);
                const vuint2 tv = *reinterpret_cast<const vuint2*>(Xp + (size_t)t * 8 + w0);
                const float* rr = &Rs[r * RPAD2 + f0];
                float acc = dot8_i8(sv, tv, *reinterpret_cast<const vfloat4*>(rr),
                                            *reinterpret_cast<const vfloat4*>(rr + 4));
                acc += __shfl_xor(acc, 1, 64);
                acc += __shfl_xor(acc, 2, 64);
                if (sub == 0) {
                    if (PHASE == 0) out[e] = acc;
                    else            out[e] = (out[e] + acc) * S[s] * S[t];
                }
            }
        }
    }
}

// ---------------- fp32 fallback ----------------
__global__ void __launch_bounds__(256) distmult_f32_kernel(
        const float* __restrict__ X, const float* __restrict__ R,
        const int* __restrict__ src, const int* __restrict__ tgt,
        const int* __restrict__ rel, float* __restrict__ out, int num_edges) {
    const int sub = threadIdx.x & 15;
    int e = blockIdx.x * 16 + (threadIdx.x >> 4);
    const int estr = gridDim.x * 16;
    for (; e < num_edges; e += estr) {
        const int s = src[e], t = tgt[e], r = rel[e];
        const float4 sv = *reinterpret_cast<const float4*>(X + (size_t)s * DIM + sub * 4);
        const float4 tv = *reinterpret_cast<const float4*>(X + (size_t)t * DIM + sub * 4);
        const float4 rv = *reinterpret_cast<const float4*>(R + (size_t)r * DIM + sub * 4);
        float acc = sv.x * rv.x * tv.x + sv.y * rv.y * tv.y
                  + sv.z * rv.z * tv.z + sv.w * rv.w * tv.w;
        acc += __shfl_xor(acc, 1, 64);
        acc += __shfl_xor(acc, 2, 64);
        acc += __shfl_xor(acc, 4, 64);
        acc += __shfl_xor(acc, 8, 64);
        if (sub == 0) out[e] = acc;
    }
}

extern "C" void kernel_launch(void* const* d_in, const int* in_sizes, int n_in,
                              void* d_out, int out_size, void* d_ws, size_t ws_size,
                              hipStream_t stream) {
    const float* X         = (const float*)d_in[0];  // (100000, 64) f32
    const float* R         = (const float*)d_in[1];  // (237, 64) f32
    const int*   edge_list = (const int*)d_in[2];    // (2, NUM_EDGES) i32
    const int*   edge_type = (const int*)d_in[3];    // (1, NUM_EDGES) i32
    float*       out       = (float*)d_out;

    const int num_edges = in_sizes[3];
    const int nx        = in_sizes[0];               // 6.4M floats
    const int nrows     = nx / DIM;                  // 100000
    const int nrel      = in_sizes[1] / DIM;         // 237
    const int* src = edge_list;
    const int* tgt = edge_list + num_edges;

    const size_t sc_bytes = ((size_t)nrows * 4 + 511) & ~(size_t)511;
    const size_t need = sc_bytes + (size_t)nx;       // scales + 2 planes (nx bytes total)
    if (ws_size >= need && (nx % DIM) == 0 && nrel <= MAX_REL) {
        float*        Sv = (float*)d_ws;
        unsigned int* Xq = (unsigned int*)((char*)d_ws + sc_bytes);

        quantize_rows_kernel<<<(nrows + 31) / 32, 256, 0, stream>>>(X, Xq, Sv, nrows);

        const int ngroups = (num_edges + 3) >> 2;
        int grid = 1024;                             // 4 blocks/CU (36 KB LDS each)
        const int max_grid = (ngroups + 127) / 128;
        if (grid > max_grid) grid = max_grid;

        distmult_i8_phase_kernel<0><<<grid, 512, 0, stream>>>(
            Xq, R, Sv, src, tgt, edge_type, out, num_edges, nrows, nrel);
        distmult_i8_phase_kernel<1><<<grid, 512, 0, stream>>>(
            Xq, R, Sv, src, tgt, edge_type, out, num_edges, nrows, nrel);
    } else {
        int grid = (num_edges + 15) / 16;
        if (grid > 8192) grid = 8192;
        distmult_f32_kernel<<<grid, 256, 0, stream>>>(
            X, R, src, tgt, edge_type, out, num_edges);
    }
}

// Round 9
// 58.249 us; speedup vs baseline: 1.0320x; 1.0320x over previous
//
#include <hip/hip_runtime.h>

#define DIM 64

typedef int          vint4   __attribute__((ext_vector_type(4)));
typedef unsigned int vuint2  __attribute__((ext_vector_type(2)));
typedef float        vfloat4 __attribute__((ext_vector_type(4)));

// ---------------- Kernel 1: fused per-row absmax + int8 quantize ----------------
__global__ void __launch_bounds__(256) quantize_rows_kernel(
        const float* __restrict__ X,      // [nrows, 64] fp32
        unsigned int* __restrict__ Xq,    // [nrows, 16] words (64 B int8 rows)
        float* __restrict__ S,            // [nrows] scale = rowmax/127
        int nrows) {
    const int row = blockIdx.x * 32 + (threadIdx.x >> 3);
    if (row >= nrows) return;
    const int sub = threadIdx.x & 7;

    const float* xr = X + (size_t)row * DIM + sub * 8;
    const vfloat4 a = *reinterpret_cast<const vfloat4*>(xr);
    const vfloat4 b = *reinterpret_cast<const vfloat4*>(xr + 4);

    unsigned int m = __float_as_uint(a.x) & 0x7fffffffu;
    m = max(m, __float_as_uint(a.y) & 0x7fffffffu);
    m = max(m, __float_as_uint(a.z) & 0x7fffffffu);
    m = max(m, __float_as_uint(a.w) & 0x7fffffffu);
    m = max(m, __float_as_uint(b.x) & 0x7fffffffu);
    m = max(m, __float_as_uint(b.y) & 0x7fffffffu);
    m = max(m, __float_as_uint(b.z) & 0x7fffffffu);
    m = max(m, __float_as_uint(b.w) & 0x7fffffffu);
    m = max(m, (unsigned int)__shfl_xor((int)m, 1, 64));
    m = max(m, (unsigned int)__shfl_xor((int)m, 2, 64));
    m = max(m, (unsigned int)__shfl_xor((int)m, 4, 64));

    const float rowmax = __uint_as_float(m);
    const float inv = (rowmax > 0.0f) ? (127.0f / rowmax) : 0.0f;

    const int q0 = (int)rintf(a.x * inv), q1 = (int)rintf(a.y * inv);
    const int q2 = (int)rintf(a.z * inv), q3 = (int)rintf(a.w * inv);
    const int q4 = (int)rintf(b.x * inv), q5 = (int)rintf(b.y * inv);
    const int q6 = (int)rintf(b.z * inv), q7 = (int)rintf(b.w * inv);
    vuint2 o;
    o.x = (unsigned int)(q0 & 0xff) | ((unsigned int)(q1 & 0xff) << 8) |
          ((unsigned int)(q2 & 0xff) << 16) | ((unsigned int)(q3 & 0xff) << 24);
    o.y = (unsigned int)(q4 & 0xff) | ((unsigned int)(q5 & 0xff) << 8) |
          ((unsigned int)(q6 & 0xff) << 16) | ((unsigned int)(q7 & 0xff) << 24);
    *reinterpret_cast<vuint2*>(Xq + (size_t)row * 16 + sub * 2) = o;

    if (sub == 0) S[row] = rowmax * (1.0f / 127.0f);
}

// ---------------- int8 dot helper ----------------
__device__ __forceinline__ float dot8_i8(const vuint2& s, const vuint2& t,
                                         const vfloat4& ra, const vfloat4& rb) {
    float acc = 0.f;
    int p;
    p = ((int)(s.x << 24) >> 24) * ((int)(t.x << 24) >> 24); acc = fmaf((float)p, ra.x, acc);
    p = ((int)(s.x << 16) >> 24) * ((int)(t.x << 16) >> 24); acc = fmaf((float)p, ra.y, acc);
    p = ((int)(s.x <<  8) >> 24) * ((int)(t.x <<  8) >> 24); acc = fmaf((float)p, ra.z, acc);
    p = ((int)(s.x      ) >> 24) * ((int)(t.x      ) >> 24); acc = fmaf((float)p, ra.w, acc);
    p = ((int)(s.y << 24) >> 24) * ((int)(t.y << 24) >> 24); acc = fmaf((float)p, rb.x, acc);
    p = ((int)(s.y << 16) >> 24) * ((int)(t.y << 16) >> 24); acc = fmaf((float)p, rb.y, acc);
    p = ((int)(s.y <<  8) >> 24) * ((int)(t.y <<  8) >> 24); acc = fmaf((float)p, rb.z, acc);
    p = ((int)(s.y      ) >> 24) * ((int)(t.y      ) >> 24); acc = fmaf((float)p, rb.w, acc);
    return acc;
}

// ---------------- Score kernel: round-6 body, round-1 launch shape ----------------
// 8 lanes/edge, 4 edges/group, 32 groups per 256-thread block,
// grid-stride over groups with a deep queued grid (occupancy lever).
__global__ void __launch_bounds__(256) distmult_i8_kernel(
        const unsigned int* __restrict__ Xq,  // [nrows, 16] words
        const float* __restrict__ R,          // [NUM_REL, 64] fp32 (hot)
        const float* __restrict__ S,          // [nrows] per-row scales
        const int*   __restrict__ src,
        const int*   __restrict__ tgt,
        const int*   __restrict__ rel,
        float*       __restrict__ out,
        int num_edges) {
    const int sub = threadIdx.x & 7;
    const int w0  = sub * 2;                  // word offset in 16-word int8 row
    const int f0  = sub * 8;                  // feature offset in fp32 R row
    int g = blockIdx.x * 32 + (threadIdx.x >> 3);
    const int gstr = gridDim.x * 32;
    const int ngroups = (num_edges + 3) >> 2;

    for (; g < ngroups; g += gstr) {
        const int e0 = g << 2;
        if (e0 + 3 < num_edges) {
            const vint4 s4 = *reinterpret_cast<const vint4*>(src + e0);
            const vint4 t4 = *reinterpret_cast<const vint4*>(tgt + e0);
            const vint4 r4 = *reinterpret_cast<const vint4*>(rel + e0);

            const vuint2 sv0 = *reinterpret_cast<const vuint2*>(Xq + (size_t)s4.x * 16 + w0);
            const vuint2 sv1 = *reinterpret_cast<const vuint2*>(Xq + (size_t)s4.y * 16 + w0);
            const vuint2 sv2 = *reinterpret_cast<const vuint2*>(Xq + (size_t)s4.z * 16 + w0);
            const vuint2 sv3 = *reinterpret_cast<const vuint2*>(Xq + (size_t)s4.w * 16 + w0);
            const vuint2 tv0 = *reinterpret_cast<const vuint2*>(Xq + (size_t)t4.x * 16 + w0);
            const vuint2 tv1 = *reinterpret_cast<const vuint2*>(Xq + (size_t)t4.y * 16 + w0);
            const vuint2 tv2 = *reinterpret_cast<const vuint2*>(Xq + (size_t)t4.z * 16 + w0);
            const vuint2 tv3 = *reinterpret_cast<const vuint2*>(Xq + (size_t)t4.w * 16 + w0);

            const float sc0 = S[s4.x] * S[t4.x];
            const float sc1 = S[s4.y] * S[t4.y];
            const float sc2 = S[s4.z] * S[t4.z];
            const float sc3 = S[s4.w] * S[t4.w];

            const vfloat4 ra0 = *reinterpret_cast<const vfloat4*>(R + (size_t)r4.x * DIM + f0);
            const vfloat4 rb0 = *reinterpret_cast<const vfloat4*>(R + (size_t)r4.x * DIM + f0 + 4);
            const vfloat4 ra1 = *reinterpret_cast<const vfloat4*>(R + (size_t)r4.y * DIM + f0);
            const vfloat4 rb1 = *reinterpret_cast<const vfloat4*>(R + (size_t)r4.y * DIM + f0 + 4);
            const vfloat4 ra2 = *reinterpret_cast<const vfloat4*>(R + (size_t)r4.z * DIM + f0);
            const vfloat4 rb2 = *reinterpret_cast<const vfloat4*>(R + (size_t)r4.z * DIM + f0 + 4);
            const vfloat4 ra3 = *reinterpret_cast<const vfloat4*>(R + (size_t)r4.w * DIM + f0);
            const vfloat4 rb3 = *reinterpret_cast<const vfloat4*>(R + (size_t)r4.w * DIM + f0 + 4);

            float a0 = dot8_i8(sv0, tv0, ra0, rb0);
            float a1 = dot8_i8(sv1, tv1, ra1, rb1);
            float a2 = dot8_i8(sv2, tv2, ra2, rb2);
            float a3 = dot8_i8(sv3, tv3, ra3, rb3);

            a0 += __shfl_xor(a0, 1, 64); a1 += __shfl_xor(a1, 1, 64);
            a2 += __shfl_xor(a2, 1, 64); a3 += __shfl_xor(a3, 1, 64);
            a0 += __shfl_xor(a0, 2, 64); a1 += __shfl_xor(a1, 2, 64);
            a2 += __shfl_xor(a2, 2, 64); a3 += __shfl_xor(a3, 2, 64);
            a0 += __shfl_xor(a0, 4, 64); a1 += __shfl_xor(a1, 4, 64);
            a2 += __shfl_xor(a2, 4, 64); a3 += __shfl_xor(a3, 4, 64);

            if (sub == 0) {
                vfloat4 o;
                o.x = a0 * sc0; o.y = a1 * sc1; o.z = a2 * sc2; o.w = a3 * sc3;
                *reinterpret_cast<vfloat4*>(out + e0) = o;
            }
        } else {
            for (int e = e0; e < num_edges; ++e) {
                const int s = src[e], t = tgt[e], r = rel[e];
                const vuint2  sv = *reinterpret_cast<const vuint2*>(Xq + (size_t)s * 16 + w0);
                const vuint2  tv = *reinterpret_cast<const vuint2*>(Xq + (size_t)t * 16 + w0);
                const vfloat4 ra = *reinterpret_cast<const vfloat4*>(R + (size_t)r * DIM + f0);
                const vfloat4 rb = *reinterpret_cast<const vfloat4*>(R + (size_t)r * DIM + f0 + 4);
                float acc = dot8_i8(sv, tv, ra, rb);
                acc += __shfl_xor(acc, 1, 64);
                acc += __shfl_xor(acc, 2, 64);
                acc += __shfl_xor(acc, 4, 64);
                if (sub == 0) out[e] = acc * S[s] * S[t];
            }
        }
    }
}

// ---------------- fp32 fallback (ws too small) ----------------
__global__ void __launch_bounds__(256) distmult_f32_kernel(
        const float* __restrict__ X, const float* __restrict__ R,
        const int* __restrict__ src, const int* __restrict__ tgt,
        const int* __restrict__ rel, float* __restrict__ out, int num_edges) {
    const int sub = threadIdx.x & 15;
    int e = blockIdx.x * 16 + (threadIdx.x >> 4);
    const int estr = gridDim.x * 16;
    for (; e < num_edges; e += estr) {
        const int s = src[e], t = tgt[e], r = rel[e];
        const float4 sv = *reinterpret_cast<const float4*>(X + (size_t)s * DIM + sub * 4);
        const float4 tv = *reinterpret_cast<const float4*>(X + (size_t)t * DIM + sub * 4);
        const float4 rv = *reinterpret_cast<const float4*>(R + (size_t)r * DIM + sub * 4);
        float acc = sv.x * rv.x * tv.x + sv.y * rv.y * tv.y
                  + sv.z * rv.z * tv.z + sv.w * rv.w * tv.w;
        acc += __shfl_xor(acc, 1, 64);
        acc += __shfl_xor(acc, 2, 64);
        acc += __shfl_xor(acc, 4, 64);
        acc += __shfl_xor(acc, 8, 64);
        if (sub == 0) out[e] = acc;
    }
}

extern "C" void kernel_launch(void* const* d_in, const int* in_sizes, int n_in,
                              void* d_out, int out_size, void* d_ws, size_t ws_size,
                              hipStream_t stream) {
    const float* X         = (const float*)d_in[0];  // (100000, 64) f32
    const float* R         = (const float*)d_in[1];  // (237, 64) f32
    const int*   edge_list = (const int*)d_in[2];    // (2, NUM_EDGES) i32
    const int*   edge_type = (const int*)d_in[3];    // (1, NUM_EDGES) i32
    float*       out       = (float*)d_out;

    const int num_edges = in_sizes[3];
    const int nx        = in_sizes[0];               // 6.4M floats
    const int nrows     = nx / DIM;                  // 100000
    const int* src = edge_list;
    const int* tgt = edge_list + num_edges;

    const size_t sc_bytes = ((size_t)nrows * 4 + 511) & ~(size_t)511;
    const size_t need = sc_bytes + (size_t)nx;
    if (ws_size >= need && (nx % DIM) == 0) {
        float*        Sv = (float*)d_ws;
        unsigned int* Xq = (unsigned int*)((char*)d_ws + sc_bytes);

        quantize_rows_kernel<<<(nrows + 31) / 32, 256, 0, stream>>>(X, Xq, Sv, nrows);

        // Occupancy lever: deep queued grid, grid-stride (~2.4 iters/block,
        // 16 blocks/CU queued) -- the only config that ever exceeded 32% occ
        // was this launch shape (round 1: 79%).
        const int ngroups = (num_edges + 3) >> 2;    // 4 edges per 8-lane group
        const int gpb = 256 / 8;                     // 32 groups per block
        int grid = 4096;
        const int max_grid = (ngroups + gpb - 1) / gpb;
        if (grid > max_grid) grid = max_grid;
        distmult_i8_kernel<<<grid, 256, 0, stream>>>(
            Xq, R, Sv, src, tgt, edge_type, out, num_edges);
    } else {
        int grid = (num_edges + 15) / 16;
        if (grid > 8192) grid = 8192;
        distmult_f32_kernel<<<grid, 256, 0, stream>>>(
            X, R, src, tgt, edge_type, out, num_edges);
    }
}

// Round 10
// 49.873 us; speedup vs baseline: 1.2053x; 1.1679x over previous
//
#include <hip/hip_runtime.h>

#define DIM 64
#define MAX_REL 256
#define RPAD 68              // padded LDS row stride in floats

typedef int          vint4   __attribute__((ext_vector_type(4)));
typedef unsigned int vuint2  __attribute__((ext_vector_type(2)));
typedef unsigned int vuint4  __attribute__((ext_vector_type(4)));
typedef float        vfloat4 __attribute__((ext_vector_type(4)));

// ---------------- Kernel A1: block-level partial absmax (no atomics) ----------------
__global__ void __launch_bounds__(256) absmax_partial_kernel(
        const float* __restrict__ X, unsigned int* __restrict__ partials, int n4) {
    __shared__ unsigned int red[4];
    const vuint4* Xu = reinterpret_cast<const vuint4*>(X);
    unsigned int m = 0;
    int i = blockIdx.x * blockDim.x + threadIdx.x;
    const int str = gridDim.x * blockDim.x;
    for (; i < n4; i += str) {
        const vuint4 v = Xu[i];
        m = max(m, v.x & 0x7fffffffu);
        m = max(m, v.y & 0x7fffffffu);
        m = max(m, v.z & 0x7fffffffu);
        m = max(m, v.w & 0x7fffffffu);
    }
    for (int off = 32; off > 0; off >>= 1)
        m = max(m, (unsigned int)__shfl_xor((int)m, off, 64));
    if ((threadIdx.x & 63) == 0) red[threadIdx.x >> 6] = m;
    __syncthreads();
    if (threadIdx.x == 0) {
        m = max(max(red[0], red[1]), max(red[2], red[3]));
        partials[blockIdx.x] = m;
    }
}

// ---------------- Kernel A2: finalize scale (1 block) ----------------
__global__ void __launch_bounds__(256) absmax_final_kernel(
        const unsigned int* __restrict__ partials, float* __restrict__ scinv, int n) {
    __shared__ unsigned int red[4];
    unsigned int m = (threadIdx.x < n) ? partials[threadIdx.x] : 0u;
    for (int off = 32; off > 0; off >>= 1)
        m = max(m, (unsigned int)__shfl_xor((int)m, off, 64));
    if ((threadIdx.x & 63) == 0) red[threadIdx.x >> 6] = m;
    __syncthreads();
    if (threadIdx.x == 0) {
        m = max(max(red[0], red[1]), max(red[2], red[3]));
        const float mx = __uint_as_float(m);
        scinv[0] = mx * (1.0f / 127.0f);                       // sc
        scinv[1] = (mx > 0.0f) ? (127.0f / mx) : 0.0f;         // inv
    }
}

// ---------------- Kernel B: quantize X -> int8 (global scale) ----------------
__device__ __forceinline__ unsigned int pack4_i8(const vfloat4& f, float inv) {
    const int q0 = (int)rintf(f.x * inv);
    const int q1 = (int)rintf(f.y * inv);
    const int q2 = (int)rintf(f.z * inv);
    const int q3 = (int)rintf(f.w * inv);
    return (unsigned int)(q0 & 0xff) | ((unsigned int)(q1 & 0xff) << 8) |
           ((unsigned int)(q2 & 0xff) << 16) | ((unsigned int)(q3 & 0xff) << 24);
}

__global__ void __launch_bounds__(256) quantize_kernel(
        const float* __restrict__ X, const float* __restrict__ scinv,
        unsigned int* __restrict__ Xq, int n16) {
    int i = blockIdx.x * blockDim.x + threadIdx.x;
    if (i >= n16) return;
    const float inv = scinv[1];
    const vfloat4* Xf = reinterpret_cast<const vfloat4*>(X);
    const vfloat4 a = Xf[(size_t)i * 4 + 0];
    const vfloat4 b = Xf[(size_t)i * 4 + 1];
    const vfloat4 c = Xf[(size_t)i * 4 + 2];
    const vfloat4 d = Xf[(size_t)i * 4 + 3];
    vuint4 o;
    o.x = pack4_i8(a, inv);
    o.y = pack4_i8(b, inv);
    o.z = pack4_i8(c, inv);
    o.w = pack4_i8(d, inv);
    reinterpret_cast<vuint4*>(Xq)[i] = o;
}

// ---------------- int8 dot helper ----------------
__device__ __forceinline__ float dot8_i8(const vuint2& s, const vuint2& t,
                                         const vfloat4& ra, const vfloat4& rb) {
    float acc = 0.f;
    int p;
    p = ((int)(s.x << 24) >> 24) * ((int)(t.x << 24) >> 24); acc = fmaf((float)p, ra.x, acc);
    p = ((int)(s.x << 16) >> 24) * ((int)(t.x << 16) >> 24); acc = fmaf((float)p, ra.y, acc);
    p = ((int)(s.x <<  8) >> 24) * ((int)(t.x <<  8) >> 24); acc = fmaf((float)p, ra.z, acc);
    p = ((int)(s.x      ) >> 24) * ((int)(t.x      ) >> 24); acc = fmaf((float)p, ra.w, acc);
    p = ((int)(s.y << 24) >> 24) * ((int)(t.y << 24) >> 24); acc = fmaf((float)p, rb.x, acc);
    p = ((int)(s.y << 16) >> 24) * ((int)(t.y << 16) >> 24); acc = fmaf((float)p, rb.y, acc);
    p = ((int)(s.y <<  8) >> 24) * ((int)(t.y <<  8) >> 24); acc = fmaf((float)p, rb.z, acc);
    p = ((int)(s.y      ) >> 24) * ((int)(t.y      ) >> 24); acc = fmaf((float)p, rb.w, acc);
    return acc;
}

// ---------------- Score kernel: round-7 structure, NO per-row scale gathers -------
// 8 lanes/edge, 4 edges/group, 64 groups per 512-thread block, persistent grid.
__global__ void __launch_bounds__(512) distmult_i8_lds_kernel(
        const unsigned int* __restrict__ Xq,  // [nrows, 16] words (64 B rows)
        const float* __restrict__ R,          // [nrel, 64] fp32
        const float* __restrict__ scinv,      // [0]=sc
        const int*   __restrict__ src,
        const int*   __restrict__ tgt,
        const int*   __restrict__ rel,
        float*       __restrict__ out,
        int num_edges, int nrel) {
    __shared__ float Rs[MAX_REL * RPAD];      // 68 KB

    for (int i = threadIdx.x; i < nrel * 16; i += 512) {
        const int r = i >> 4, c = (i & 15) * 4;
        *reinterpret_cast<vfloat4*>(&Rs[r * RPAD + c]) =
            *reinterpret_cast<const vfloat4*>(R + (size_t)r * DIM + c);
    }
    __syncthreads();

    const float sc  = scinv[0];
    const float sc2 = sc * sc;

    const int sub = threadIdx.x & 7;
    const int w0  = sub * 2;
    const int f0  = sub * 8;
    int g = blockIdx.x * 64 + (threadIdx.x >> 3);
    const int gstr = gridDim.x * 64;
    const int ngroups = (num_edges + 3) >> 2;

    for (; g < ngroups; g += gstr) {
        const int e0 = g << 2;
        if (e0 + 3 < num_edges) {
            const vint4 s4 = *reinterpret_cast<const vint4*>(src + e0);
            const vint4 t4 = *reinterpret_cast<const vint4*>(tgt + e0);
            const vint4 r4 = *reinterpret_cast<const vint4*>(rel + e0);

            const vuint2 sv0 = *reinterpret_cast<const vuint2*>(Xq + (size_t)s4.x * 16 + w0);
            const vuint2 sv1 = *reinterpret_cast<const vuint2*>(Xq + (size_t)s4.y * 16 + w0);
            const vuint2 sv2 = *reinterpret_cast<const vuint2*>(Xq + (size_t)s4.z * 16 + w0);
            const vuint2 sv3 = *reinterpret_cast<const vuint2*>(Xq + (size_t)s4.w * 16 + w0);
            const vuint2 tv0 = *reinterpret_cast<const vuint2*>(Xq + (size_t)t4.x * 16 + w0);
            const vuint2 tv1 = *reinterpret_cast<const vuint2*>(Xq + (size_t)t4.y * 16 + w0);
            const vuint2 tv2 = *reinterpret_cast<const vuint2*>(Xq + (size_t)t4.z * 16 + w0);
            const vuint2 tv3 = *reinterpret_cast<const vuint2*>(Xq + (size_t)t4.w * 16 + w0);

            const float* r0 = &Rs[r4.x * RPAD + f0];
            const float* r1 = &Rs[r4.y * RPAD + f0];
            const float* r2 = &Rs[r4.z * RPAD + f0];
            const float* r3 = &Rs[r4.w * RPAD + f0];

            float a0 = dot8_i8(sv0, tv0, *reinterpret_cast<const vfloat4*>(r0),
                                          *reinterpret_cast<const vfloat4*>(r0 + 4));
            float a1 = dot8_i8(sv1, tv1, *reinterpret_cast<const vfloat4*>(r1),
                                          *reinterpret_cast<const vfloat4*>(r1 + 4));
            float a2 = dot8_i8(sv2, tv2, *reinterpret_cast<const vfloat4*>(r2),
                                          *reinterpret_cast<const vfloat4*>(r2 + 4));
            float a3 = dot8_i8(sv3, tv3, *reinterpret_cast<const vfloat4*>(r3),
                                          *reinterpret_cast<const vfloat4*>(r3 + 4));

            a0 += __shfl_xor(a0, 1, 64); a1 += __shfl_xor(a1, 1, 64);
            a2 += __shfl_xor(a2, 1, 64); a3 += __shfl_xor(a3, 1, 64);
            a0 += __shfl_xor(a0, 2, 64); a1 += __shfl_xor(a1, 2, 64);
            a2 += __shfl_xor(a2, 2, 64); a3 += __shfl_xor(a3, 2, 64);
            a0 += __shfl_xor(a0, 4, 64); a1 += __shfl_xor(a1, 4, 64);
            a2 += __shfl_xor(a2, 4, 64); a3 += __shfl_xor(a3, 4, 64);

            if (sub == 0) {
                vfloat4 o;
                o.x = a0 * sc2; o.y = a1 * sc2; o.z = a2 * sc2; o.w = a3 * sc2;
                *reinterpret_cast<vfloat4*>(out + e0) = o;
            }
        } else {
            for (int e = e0; e < num_edges; ++e) {
                const int s = src[e], t = tgt[e], r = rel[e];
                const vuint2 sv = *reinterpret_cast<const vuint2*>(Xq + (size_t)s * 16 + w0);
                const vuint2 tv = *reinterpret_cast<const vuint2*>(Xq + (size_t)t * 16 + w0);
                const float* rr = &Rs[r * RPAD + f0];
                float acc = dot8_i8(sv, tv, *reinterpret_cast<const vfloat4*>(rr),
                                            *reinterpret_cast<const vfloat4*>(rr + 4));
                acc += __shfl_xor(acc, 1, 64);
                acc += __shfl_xor(acc, 2, 64);
                acc += __shfl_xor(acc, 4, 64);
                if (sub == 0) out[e] = acc * sc2;
            }
        }
    }
}

// ---------------- fp32 fallback ----------------
__global__ void __launch_bounds__(256) distmult_f32_kernel(
        const float* __restrict__ X, const float* __restrict__ R,
        const int* __restrict__ src, const int* __restrict__ tgt,
        const int* __restrict__ rel, float* __restrict__ out, int num_edges) {
    const int sub = threadIdx.x & 15;
    int e = blockIdx.x * 16 + (threadIdx.x >> 4);
    const int estr = gridDim.x * 16;
    for (; e < num_edges; e += estr) {
        const int s = src[e], t = tgt[e], r = rel[e];
        const float4 sv = *reinterpret_cast<const float4*>(X + (size_t)s * DIM + sub * 4);
        const float4 tv = *reinterpret_cast<const float4*>(X + (size_t)t * DIM + sub * 4);
        const float4 rv = *reinterpret_cast<const float4*>(R + (size_t)r * DIM + sub * 4);
        float acc = sv.x * rv.x * tv.x + sv.y * rv.y * tv.y
                  + sv.z * rv.z * tv.z + sv.w * rv.w * tv.w;
        acc += __shfl_xor(acc, 1, 64);
        acc += __shfl_xor(acc, 2, 64);
        acc += __shfl_xor(acc, 4, 64);
        acc += __shfl_xor(acc, 8, 64);
        if (sub == 0) out[e] = acc;
    }
}

extern "C" void kernel_launch(void* const* d_in, const int* in_sizes, int n_in,
                              void* d_out, int out_size, void* d_ws, size_t ws_size,
                              hipStream_t stream) {
    const float* X         = (const float*)d_in[0];  // (100000, 64) f32
    const float* R         = (const float*)d_in[1];  // (237, 64) f32
    const int*   edge_list = (const int*)d_in[2];    // (2, NUM_EDGES) i32
    const int*   edge_type = (const int*)d_in[3];    // (1, NUM_EDGES) i32
    float*       out       = (float*)d_out;

    const int num_edges = in_sizes[3];
    const int nx        = in_sizes[0];               // 6.4M floats
    const int nrel      = in_sizes[1] / DIM;         // 237
    const int* src = edge_list;
    const int* tgt = edge_list + num_edges;

    // ws layout: [0,8) = {sc, inv}; [256,1280) = 256 partials; [2048, 2048+nx) = Xq
    const size_t need = 2048 + (size_t)nx;
    if (ws_size >= need && (nx % 16) == 0 && nrel <= MAX_REL) {
        float*        scinv    = (float*)d_ws;
        unsigned int* partials = (unsigned int*)((char*)d_ws + 256);
        unsigned int* Xq       = (unsigned int*)((char*)d_ws + 2048);

        // deterministic two-stage absmax (no atomics)
        absmax_partial_kernel<<<256, 256, 0, stream>>>(X, partials, nx / 4);
        absmax_final_kernel<<<1, 256, 0, stream>>>(partials, scinv, 256);

        const int n16 = nx / 16;
        quantize_kernel<<<(n16 + 255) / 256, 256, 0, stream>>>(X, scinv, Xq, n16);

        // round-7 launch shape: 512 threads, persistent grid 512 (2 blocks/CU)
        const int ngroups = (num_edges + 3) >> 2;
        int grid = 512;
        const int max_grid = (ngroups + 63) / 64;
        if (grid > max_grid) grid = max_grid;
        distmult_i8_lds_kernel<<<grid, 512, 0, stream>>>(
            Xq, R, scinv, src, tgt, edge_type, out, num_edges, nrel);
    } else {
        int grid = (num_edges + 15) / 16;
        if (grid > 8192) grid = 8192;
        distmult_f32_kernel<<<grid, 256, 0, stream>>>(
            X, R, src, tgt, edge_type, out, num_edges);
    }
}

// Round 11
// 47.661 us; speedup vs baseline: 1.2613x; 1.0464x over previous
//
#include <hip/hip_runtime.h>

#define DIM 64
#define MAX_REL 256
#define RPAD 68              // padded LDS row stride in floats

typedef int          vint4   __attribute__((ext_vector_type(4)));
typedef unsigned int vuint2  __attribute__((ext_vector_type(2)));
typedef unsigned int vuint4  __attribute__((ext_vector_type(4)));
typedef float        vfloat4 __attribute__((ext_vector_type(4)));

// ---------------- Kernel A1: block-level partial absmax (no atomics) ----------------
__global__ void __launch_bounds__(256) absmax_partial_kernel(
        const float* __restrict__ X, unsigned int* __restrict__ partials, int n4) {
    __shared__ unsigned int red[4];
    const vuint4* Xu = reinterpret_cast<const vuint4*>(X);
    unsigned int m = 0;
    int i = blockIdx.x * blockDim.x + threadIdx.x;
    const int str = gridDim.x * blockDim.x;
    for (; i < n4; i += str) {
        const vuint4 v = Xu[i];
        m = max(m, v.x & 0x7fffffffu);
        m = max(m, v.y & 0x7fffffffu);
        m = max(m, v.z & 0x7fffffffu);
        m = max(m, v.w & 0x7fffffffu);
    }
    for (int off = 32; off > 0; off >>= 1)
        m = max(m, (unsigned int)__shfl_xor((int)m, off, 64));
    if ((threadIdx.x & 63) == 0) red[threadIdx.x >> 6] = m;
    __syncthreads();
    if (threadIdx.x == 0) {
        m = max(max(red[0], red[1]), max(red[2], red[3]));
        partials[blockIdx.x] = m;
    }
}

// ---------------- Kernel A2: finalize scale (1 block) ----------------
__global__ void __launch_bounds__(256) absmax_final_kernel(
        const unsigned int* __restrict__ partials, float* __restrict__ scinv, int n) {
    __shared__ unsigned int red[4];
    unsigned int m = (threadIdx.x < n) ? partials[threadIdx.x] : 0u;
    for (int off = 32; off > 0; off >>= 1)
        m = max(m, (unsigned int)__shfl_xor((int)m, off, 64));
    if ((threadIdx.x & 63) == 0) red[threadIdx.x >> 6] = m;
    __syncthreads();
    if (threadIdx.x == 0) {
        m = max(max(red[0], red[1]), max(red[2], red[3]));
        const float mx = __uint_as_float(m);
        scinv[0] = mx * (1.0f / 127.0f);                       // sc
        scinv[1] = (mx > 0.0f) ? (127.0f / mx) : 0.0f;         // inv
    }
}

// ---------------- Kernel B: quantize X -> int8 (global scale) ----------------
__device__ __forceinline__ unsigned int pack4_i8(const vfloat4& f, float inv) {
    const int q0 = (int)rintf(f.x * inv);
    const int q1 = (int)rintf(f.y * inv);
    const int q2 = (int)rintf(f.z * inv);
    const int q3 = (int)rintf(f.w * inv);
    return (unsigned int)(q0 & 0xff) | ((unsigned int)(q1 & 0xff) << 8) |
           ((unsigned int)(q2 & 0xff) << 16) | ((unsigned int)(q3 & 0xff) << 24);
}

__global__ void __launch_bounds__(256) quantize_kernel(
        const float* __restrict__ X, const float* __restrict__ scinv,
        unsigned int* __restrict__ Xq, int n16) {
    int i = blockIdx.x * blockDim.x + threadIdx.x;
    if (i >= n16) return;
    const float inv = scinv[1];
    const vfloat4* Xf = reinterpret_cast<const vfloat4*>(X);
    const vfloat4 a = Xf[(size_t)i * 4 + 0];
    const vfloat4 b = Xf[(size_t)i * 4 + 1];
    const vfloat4 c = Xf[(size_t)i * 4 + 2];
    const vfloat4 d = Xf[(size_t)i * 4 + 3];
    vuint4 o;
    o.x = pack4_i8(a, inv);
    o.y = pack4_i8(b, inv);
    o.z = pack4_i8(c, inv);
    o.w = pack4_i8(d, inv);
    reinterpret_cast<vuint4*>(Xq)[i] = o;
}

// ---------------- int8 dot helper ----------------
__device__ __forceinline__ float dot8_i8(const vuint2& s, const vuint2& t,
                                         const vfloat4& ra, const vfloat4& rb) {
    float acc = 0.f;
    int p;
    p = ((int)(s.x << 24) >> 24) * ((int)(t.x << 24) >> 24); acc = fmaf((float)p, ra.x, acc);
    p = ((int)(s.x << 16) >> 24) * ((int)(t.x << 16) >> 24); acc = fmaf((float)p, ra.y, acc);
    p = ((int)(s.x <<  8) >> 24) * ((int)(t.x <<  8) >> 24); acc = fmaf((float)p, ra.z, acc);
    p = ((int)(s.x      ) >> 24) * ((int)(t.x      ) >> 24); acc = fmaf((float)p, ra.w, acc);
    p = ((int)(s.y << 24) >> 24) * ((int)(t.y << 24) >> 24); acc = fmaf((float)p, rb.x, acc);
    p = ((int)(s.y << 16) >> 24) * ((int)(t.y << 16) >> 24); acc = fmaf((float)p, rb.y, acc);
    p = ((int)(s.y <<  8) >> 24) * ((int)(t.y <<  8) >> 24); acc = fmaf((float)p, rb.z, acc);
    p = ((int)(s.y      ) >> 24) * ((int)(t.y      ) >> 24); acc = fmaf((float)p, rb.w, acc);
    return acc;
}

// ---------------- Score kernel: round-10 body at 1024 threads ------------------
// 8 lanes/edge, 4 edges/group, 128 groups per 1024-thread block.
// 68 KB LDS -> 2 blocks/CU -> 32 waves/CU (the HW cap; was 16 at 512 thr).
__global__ void __launch_bounds__(1024, 8) distmult_i8_lds_kernel(
        const unsigned int* __restrict__ Xq,  // [nrows, 16] words (64 B rows)
        const float* __restrict__ R,          // [nrel, 64] fp32
        const float* __restrict__ scinv,      // [0]=sc
        const int*   __restrict__ src,
        const int*   __restrict__ tgt,
        const int*   __restrict__ rel,
        float*       __restrict__ out,
        int num_edges, int nrel) {
    __shared__ float Rs[MAX_REL * RPAD];      // 68 KB

    for (int i = threadIdx.x; i < nrel * 16; i += 1024) {
        const int r = i >> 4, c = (i & 15) * 4;
        *reinterpret_cast<vfloat4*>(&Rs[r * RPAD + c]) =
            *reinterpret_cast<const vfloat4*>(R + (size_t)r * DIM + c);
    }
    __syncthreads();

    const float sc  = scinv[0];
    const float sc2 = sc * sc;

    const int sub = threadIdx.x & 7;
    const int w0  = sub * 2;
    const int f0  = sub * 8;
    int g = blockIdx.x * 128 + (threadIdx.x >> 3);
    const int gstr = gridDim.x * 128;
    const int ngroups = (num_edges + 3) >> 2;

    for (; g < ngroups; g += gstr) {
        const int e0 = g << 2;
        if (e0 + 3 < num_edges) {
            const vint4 s4 = *reinterpret_cast<const vint4*>(src + e0);
            const vint4 t4 = *reinterpret_cast<const vint4*>(tgt + e0);
            const vint4 r4 = *reinterpret_cast<const vint4*>(rel + e0);

            const vuint2 sv0 = *reinterpret_cast<const vuint2*>(Xq + (size_t)s4.x * 16 + w0);
            const vuint2 sv1 = *reinterpret_cast<const vuint2*>(Xq + (size_t)s4.y * 16 + w0);
            const vuint2 sv2 = *reinterpret_cast<const vuint2*>(Xq + (size_t)s4.z * 16 + w0);
            const vuint2 sv3 = *reinterpret_cast<const vuint2*>(Xq + (size_t)s4.w * 16 + w0);
            const vuint2 tv0 = *reinterpret_cast<const vuint2*>(Xq + (size_t)t4.x * 16 + w0);
            const vuint2 tv1 = *reinterpret_cast<const vuint2*>(Xq + (size_t)t4.y * 16 + w0);
            const vuint2 tv2 = *reinterpret_cast<const vuint2*>(Xq + (size_t)t4.z * 16 + w0);
            const vuint2 tv3 = *reinterpret_cast<const vuint2*>(Xq + (size_t)t4.w * 16 + w0);

            const float* r0 = &Rs[r4.x * RPAD + f0];
            const float* r1 = &Rs[r4.y * RPAD + f0];
            const float* r2 = &Rs[r4.z * RPAD + f0];
            const float* r3 = &Rs[r4.w * RPAD + f0];

            float a0 = dot8_i8(sv0, tv0, *reinterpret_cast<const vfloat4*>(r0),
                                          *reinterpret_cast<const vfloat4*>(r0 + 4));
            float a1 = dot8_i8(sv1, tv1, *reinterpret_cast<const vfloat4*>(r1),
                                          *reinterpret_cast<const vfloat4*>(r1 + 4));
            float a2 = dot8_i8(sv2, tv2, *reinterpret_cast<const vfloat4*>(r2),
                                          *reinterpret_cast<const vfloat4*>(r2 + 4));
            float a3 = dot8_i8(sv3, tv3, *reinterpret_cast<const vfloat4*>(r3),
                                          *reinterpret_cast<const vfloat4*>(r3 + 4));

            a0 += __shfl_xor(a0, 1, 64); a1 += __shfl_xor(a1, 1, 64);
            a2 += __shfl_xor(a2, 1, 64); a3 += __shfl_xor(a3, 1, 64);
            a0 += __shfl_xor(a0, 2, 64); a1 += __shfl_xor(a1, 2, 64);
            a2 += __shfl_xor(a2, 2, 64); a3 += __shfl_xor(a3, 2, 64);
            a0 += __shfl_xor(a0, 4, 64); a1 += __shfl_xor(a1, 4, 64);
            a2 += __shfl_xor(a2, 4, 64); a3 += __shfl_xor(a3, 4, 64);

            if (sub == 0) {
                vfloat4 o;
                o.x = a0 * sc2; o.y = a1 * sc2; o.z = a2 * sc2; o.w = a3 * sc2;
                *reinterpret_cast<vfloat4*>(out + e0) = o;
            }
        } else {
            for (int e = e0; e < num_edges; ++e) {
                const int s = src[e], t = tgt[e], r = rel[e];
                const vuint2 sv = *reinterpret_cast<const vuint2*>(Xq + (size_t)s * 16 + w0);
                const vuint2 tv = *reinterpret_cast<const vuint2*>(Xq + (size_t)t * 16 + w0);
                const float* rr = &Rs[r * RPAD + f0];
                float acc = dot8_i8(sv, tv, *reinterpret_cast<const vfloat4*>(rr),
                                            *reinterpret_cast<const vfloat4*>(rr + 4));
                acc += __shfl_xor(acc, 1, 64);
                acc += __shfl_xor(acc, 2, 64);
                acc += __shfl_xor(acc, 4, 64);
                if (sub == 0) out[e] = acc * sc2;
            }
        }
    }
}

// ---------------- fp32 fallback ----------------
__global__ void __launch_bounds__(256) distmult_f32_kernel(
        const float* __restrict__ X, const float* __restrict__ R,
        const int* __restrict__ src, const int* __restrict__ tgt,
        const int* __restrict__ rel, float* __restrict__ out, int num_edges) {
    const int sub = threadIdx.x & 15;
    int e = blockIdx.x * 16 + (threadIdx.x >> 4);
    const int estr = gridDim.x * 16;
    for (; e < num_edges; e += estr) {
        const int s = src[e], t = tgt[e], r = rel[e];
        const float4 sv = *reinterpret_cast<const float4*>(X + (size_t)s * DIM + sub * 4);
        const float4 tv = *reinterpret_cast<const float4*>(X + (size_t)t * DIM + sub * 4);
        const float4 rv = *reinterpret_cast<const float4*>(R + (size_t)r * DIM + sub * 4);
        float acc = sv.x * rv.x * tv.x + sv.y * rv.y * tv.y
                  + sv.z * rv.z * tv.z + sv.w * rv.w * tv.w;
        acc += __shfl_xor(acc, 1, 64);
        acc += __shfl_xor(acc, 2, 64);
        acc += __shfl_xor(acc, 4, 64);
        acc += __shfl_xor(acc, 8, 64);
        if (sub == 0) out[e] = acc;
    }
}

extern "C" void kernel_launch(void* const* d_in, const int* in_sizes, int n_in,
                              void* d_out, int out_size, void* d_ws, size_t ws_size,
                              hipStream_t stream) {
    const float* X         = (const float*)d_in[0];  // (100000, 64) f32
    const float* R         = (const float*)d_in[1];  // (237, 64) f32
    const int*   edge_list = (const int*)d_in[2];    // (2, NUM_EDGES) i32
    const int*   edge_type = (const int*)d_in[3];    // (1, NUM_EDGES) i32
    float*       out       = (float*)d_out;

    const int num_edges = in_sizes[3];
    const int nx        = in_sizes[0];               // 6.4M floats
    const int nrel      = in_sizes[1] / DIM;         // 237
    const int* src = edge_list;
    const int* tgt = edge_list + num_edges;

    // ws layout: [0,8) = {sc, inv}; [256,1280) = 256 partials; [2048, 2048+nx) = Xq
    const size_t need = 2048 + (size_t)nx;
    if (ws_size >= need && (nx % 16) == 0 && nrel <= MAX_REL) {
        float*        scinv    = (float*)d_ws;
        unsigned int* partials = (unsigned int*)((char*)d_ws + 256);
        unsigned int* Xq       = (unsigned int*)((char*)d_ws + 2048);

        absmax_partial_kernel<<<256, 256, 0, stream>>>(X, partials, nx / 4);
        absmax_final_kernel<<<1, 256, 0, stream>>>(partials, scinv, 256);

        const int n16 = nx / 16;
        quantize_kernel<<<(n16 + 255) / 256, 256, 0, stream>>>(X, scinv, Xq, n16);

        // 1024-thread blocks, 68 KB LDS -> 2 blocks/CU -> 32 waves/CU (cap).
        const int ngroups = (num_edges + 3) >> 2;
        int grid = 512;                              // 2 persistent blocks per CU
        const int max_grid = (ngroups + 127) / 128;
        if (grid > max_grid) grid = max_grid;
        distmult_i8_lds_kernel<<<grid, 1024, 0, stream>>>(
            Xq, R, scinv, src, tgt, edge_type, out, num_edges, nrel);
    } else {
        int grid = (num_edges + 15) / 16;
        if (grid > 8192) grid = 8192;
        distmult_f32_kernel<<<grid, 256, 0, stream>>>(
            X, R, src, tgt, edge_type, out, num_edges);
    }
}

// Round 12
// 45.009 us; speedup vs baseline: 1.3356x; 1.0589x over previous
//
#include <hip/hip_runtime.h>

#define DIM 64
#define MAX_REL 256
#define RPAD 68              // padded LDS row stride in floats
#define ABS_BLOCKS 2048      // streaming-occupancy grid for the absmax pass

typedef int          vint4   __attribute__((ext_vector_type(4)));
typedef unsigned int vuint2  __attribute__((ext_vector_type(2)));
typedef unsigned int vuint4  __attribute__((ext_vector_type(4)));
typedef float        vfloat4 __attribute__((ext_vector_type(4)));

// ---------------- Kernel A1: block-level partial absmax (no atomics) ----------------
__global__ void __launch_bounds__(256) absmax_partial_kernel(
        const float* __restrict__ X, unsigned int* __restrict__ partials, int n4) {
    __shared__ unsigned int red[4];
    const vuint4* Xu = reinterpret_cast<const vuint4*>(X);
    unsigned int m = 0;
    int i = blockIdx.x * blockDim.x + threadIdx.x;
    const int str = gridDim.x * blockDim.x;
    for (; i < n4; i += str) {
        const vuint4 v = Xu[i];
        m = max(m, v.x & 0x7fffffffu);
        m = max(m, v.y & 0x7fffffffu);
        m = max(m, v.z & 0x7fffffffu);
        m = max(m, v.w & 0x7fffffffu);
    }
    for (int off = 32; off > 0; off >>= 1)
        m = max(m, (unsigned int)__shfl_xor((int)m, off, 64));
    if ((threadIdx.x & 63) == 0) red[threadIdx.x >> 6] = m;
    __syncthreads();
    if (threadIdx.x == 0) {
        m = max(max(red[0], red[1]), max(red[2], red[3]));
        partials[blockIdx.x] = m;
    }
}

// ---------------- Kernel A2: finalize scale (1 block, loops over partials) ----------
__global__ void __launch_bounds__(256) absmax_final_kernel(
        const unsigned int* __restrict__ partials, float* __restrict__ scinv, int n) {
    __shared__ unsigned int red[4];
    unsigned int m = 0;
    for (int i = threadIdx.x; i < n; i += 256) m = max(m, partials[i]);
    for (int off = 32; off > 0; off >>= 1)
        m = max(m, (unsigned int)__shfl_xor((int)m, off, 64));
    if ((threadIdx.x & 63) == 0) red[threadIdx.x >> 6] = m;
    __syncthreads();
    if (threadIdx.x == 0) {
        m = max(max(red[0], red[1]), max(red[2], red[3]));
        const float mx = __uint_as_float(m);
        scinv[0] = mx * (1.0f / 127.0f);                       // sc
        scinv[1] = (mx > 0.0f) ? (127.0f / mx) : 0.0f;         // inv
    }
}

// ---------------- Kernel B: quantize X -> int8 (global scale) ----------------
__device__ __forceinline__ unsigned int pack4_i8(const vfloat4& f, float inv) {
    const int q0 = (int)rintf(f.x * inv);
    const int q1 = (int)rintf(f.y * inv);
    const int q2 = (int)rintf(f.z * inv);
    const int q3 = (int)rintf(f.w * inv);
    return (unsigned int)(q0 & 0xff) | ((unsigned int)(q1 & 0xff) << 8) |
           ((unsigned int)(q2 & 0xff) << 16) | ((unsigned int)(q3 & 0xff) << 24);
}

__global__ void __launch_bounds__(256) quantize_kernel(
        const float* __restrict__ X, const float* __restrict__ scinv,
        unsigned int* __restrict__ Xq, int n16) {
    int i = blockIdx.x * blockDim.x + threadIdx.x;
    if (i >= n16) return;
    const float inv = scinv[1];
    const vfloat4* Xf = reinterpret_cast<const vfloat4*>(X);
    const vfloat4 a = Xf[(size_t)i * 4 + 0];
    const vfloat4 b = Xf[(size_t)i * 4 + 1];
    const vfloat4 c = Xf[(size_t)i * 4 + 2];
    const vfloat4 d = Xf[(size_t)i * 4 + 3];
    vuint4 o;
    o.x = pack4_i8(a, inv);
    o.y = pack4_i8(b, inv);
    o.z = pack4_i8(c, inv);
    o.w = pack4_i8(d, inv);
    reinterpret_cast<vuint4*>(Xq)[i] = o;
}

// ---------------- int8 dot helper ----------------
__device__ __forceinline__ float dot8_i8(const vuint2& s, const vuint2& t,
                                         const vfloat4& ra, const vfloat4& rb) {
    float acc = 0.f;
    int p;
    p = ((int)(s.x << 24) >> 24) * ((int)(t.x << 24) >> 24); acc = fmaf((float)p, ra.x, acc);
    p = ((int)(s.x << 16) >> 24) * ((int)(t.x << 16) >> 24); acc = fmaf((float)p, ra.y, acc);
    p = ((int)(s.x <<  8) >> 24) * ((int)(t.x <<  8) >> 24); acc = fmaf((float)p, ra.z, acc);
    p = ((int)(s.x      ) >> 24) * ((int)(t.x      ) >> 24); acc = fmaf((float)p, ra.w, acc);
    p = ((int)(s.y << 24) >> 24) * ((int)(t.y << 24) >> 24); acc = fmaf((float)p, rb.x, acc);
    p = ((int)(s.y << 16) >> 24) * ((int)(t.y << 16) >> 24); acc = fmaf((float)p, rb.y, acc);
    p = ((int)(s.y <<  8) >> 24) * ((int)(t.y <<  8) >> 24); acc = fmaf((float)p, rb.z, acc);
    p = ((int)(s.y      ) >> 24) * ((int)(t.y      ) >> 24); acc = fmaf((float)p, rb.w, acc);
    return acc;
}

// ---------------- Score kernel: unchanged from round 11 (at its gather floor) -----
__global__ void __launch_bounds__(1024, 8) distmult_i8_lds_kernel(
        const unsigned int* __restrict__ Xq,  // [nrows, 16] words (64 B rows)
        const float* __restrict__ R,          // [nrel, 64] fp32
        const float* __restrict__ scinv,      // [0]=sc
        const int*   __restrict__ src,
        const int*   __restrict__ tgt,
        const int*   __restrict__ rel,
        float*       __restrict__ out,
        int num_edges, int nrel) {
    __shared__ float Rs[MAX_REL * RPAD];      // 68 KB

    for (int i = threadIdx.x; i < nrel * 16; i += 1024) {
        const int r = i >> 4, c = (i & 15) * 4;
        *reinterpret_cast<vfloat4*>(&Rs[r * RPAD + c]) =
            *reinterpret_cast<const vfloat4*>(R + (size_t)r * DIM + c);
    }
    __syncthreads();

    const float sc  = scinv[0];
    const float sc2 = sc * sc;

    const int sub = threadIdx.x & 7;
    const int w0  = sub * 2;
    const int f0  = sub * 8;
    int g = blockIdx.x * 128 + (threadIdx.x >> 3);
    const int gstr = gridDim.x * 128;
    const int ngroups = (num_edges + 3) >> 2;

    for (; g < ngroups; g += gstr) {
        const int e0 = g << 2;
        if (e0 + 3 < num_edges) {
            const vint4 s4 = *reinterpret_cast<const vint4*>(src + e0);
            const vint4 t4 = *reinterpret_cast<const vint4*>(tgt + e0);
            const vint4 r4 = *reinterpret_cast<const vint4*>(rel + e0);

            const vuint2 sv0 = *reinterpret_cast<const vuint2*>(Xq + (size_t)s4.x * 16 + w0);
            const vuint2 sv1 = *reinterpret_cast<const vuint2*>(Xq + (size_t)s4.y * 16 + w0);
            const vuint2 sv2 = *reinterpret_cast<const vuint2*>(Xq + (size_t)s4.z * 16 + w0);
            const vuint2 sv3 = *reinterpret_cast<const vuint2*>(Xq + (size_t)s4.w * 16 + w0);
            const vuint2 tv0 = *reinterpret_cast<const vuint2*>(Xq + (size_t)t4.x * 16 + w0);
            const vuint2 tv1 = *reinterpret_cast<const vuint2*>(Xq + (size_t)t4.y * 16 + w0);
            const vuint2 tv2 = *reinterpret_cast<const vuint2*>(Xq + (size_t)t4.z * 16 + w0);
            const vuint2 tv3 = *reinterpret_cast<const vuint2*>(Xq + (size_t)t4.w * 16 + w0);

            const float* r0 = &Rs[r4.x * RPAD + f0];
            const float* r1 = &Rs[r4.y * RPAD + f0];
            const float* r2 = &Rs[r4.z * RPAD + f0];
            const float* r3 = &Rs[r4.w * RPAD + f0];

            float a0 = dot8_i8(sv0, tv0, *reinterpret_cast<const vfloat4*>(r0),
                                          *reinterpret_cast<const vfloat4*>(r0 + 4));
            float a1 = dot8_i8(sv1, tv1, *reinterpret_cast<const vfloat4*>(r1),
                                          *reinterpret_cast<const vfloat4*>(r1 + 4));
            float a2 = dot8_i8(sv2, tv2, *reinterpret_cast<const vfloat4*>(r2),
                                          *reinterpret_cast<const vfloat4*>(r2 + 4));
            float a3 = dot8_i8(sv3, tv3, *reinterpret_cast<const vfloat4*>(r3),
                                          *reinterpret_cast<const vfloat4*>(r3 + 4));

            a0 += __shfl_xor(a0, 1, 64); a1 += __shfl_xor(a1, 1, 64);
            a2 += __shfl_xor(a2, 1, 64); a3 += __shfl_xor(a3, 1, 64);
            a0 += __shfl_xor(a0, 2, 64); a1 += __shfl_xor(a1, 2, 64);
            a2 += __shfl_xor(a2, 2, 64); a3 += __shfl_xor(a3, 2, 64);
            a0 += __shfl_xor(a0, 4, 64); a1 += __shfl_xor(a1, 4, 64);
            a2 += __shfl_xor(a2, 4, 64); a3 += __shfl_xor(a3, 4, 64);

            if (sub == 0) {
                vfloat4 o;
                o.x = a0 * sc2; o.y = a1 * sc2; o.z = a2 * sc2; o.w = a3 * sc2;
                *reinterpret_cast<vfloat4*>(out + e0) = o;
            }
        } else {
            for (int e = e0; e < num_edges; ++e) {
                const int s = src[e], t = tgt[e], r = rel[e];
                const vuint2 sv = *reinterpret_cast<const vuint2*>(Xq + (size_t)s * 16 + w0);
                const vuint2 tv = *reinterpret_cast<const vuint2*>(Xq + (size_t)t * 16 + w0);
                const float* rr = &Rs[r * RPAD + f0];
                float acc = dot8_i8(sv, tv, *reinterpret_cast<const vfloat4*>(rr),
                                            *reinterpret_cast<const vfloat4*>(rr + 4));
                acc += __shfl_xor(acc, 1, 64);
                acc += __shfl_xor(acc, 2, 64);
                acc += __shfl_xor(acc, 4, 64);
                if (sub == 0) out[e] = acc * sc2;
            }
        }
    }
}

// ---------------- fp32 fallback ----------------
__global__ void __launch_bounds__(256) distmult_f32_kernel(
        const float* __restrict__ X, const float* __restrict__ R,
        const int* __restrict__ src, const int* __restrict__ tgt,
        const int* __restrict__ rel, float* __restrict__ out, int num_edges) {
    const int sub = threadIdx.x & 15;
    int e = blockIdx.x * 16 + (threadIdx.x >> 4);
    const int estr = gridDim.x * 16;
    for (; e < num_edges; e += estr) {
        const int s = src[e], t = tgt[e], r = rel[e];
        const float4 sv = *reinterpret_cast<const float4*>(X + (size_t)s * DIM + sub * 4);
        const float4 tv = *reinterpret_cast<const float4*>(X + (size_t)t * DIM + sub * 4);
        const float4 rv = *reinterpret_cast<const float4*>(R + (size_t)r * DIM + sub * 4);
        float acc = sv.x * rv.x * tv.x + sv.y * rv.y * tv.y
                  + sv.z * rv.z * tv.z + sv.w * rv.w * tv.w;
        acc += __shfl_xor(acc, 1, 64);
        acc += __shfl_xor(acc, 2, 64);
        acc += __shfl_xor(acc, 4, 64);
        acc += __shfl_xor(acc, 8, 64);
        if (sub == 0) out[e] = acc;
    }
}

extern "C" void kernel_launch(void* const* d_in, const int* in_sizes, int n_in,
                              void* d_out, int out_size, void* d_ws, size_t ws_size,
                              hipStream_t stream) {
    const float* X         = (const float*)d_in[0];  // (100000, 64) f32
    const float* R         = (const float*)d_in[1];  // (237, 64) f32
    const int*   edge_list = (const int*)d_in[2];    // (2, NUM_EDGES) i32
    const int*   edge_type = (const int*)d_in[3];    // (1, NUM_EDGES) i32
    float*       out       = (float*)d_out;

    const int num_edges = in_sizes[3];
    const int nx        = in_sizes[0];               // 6.4M floats
    const int nrel      = in_sizes[1] / DIM;         // 237
    const int* src = edge_list;
    const int* tgt = edge_list + num_edges;

    // ws layout: [0,8) = {sc, inv}; [256, 256+8K) = partials; [16K, 16K+nx) = Xq
    const size_t need = 16384 + (size_t)nx;
    if (ws_size >= need && (nx % 16) == 0 && nrel <= MAX_REL) {
        float*        scinv    = (float*)d_ws;
        unsigned int* partials = (unsigned int*)((char*)d_ws + 256);
        unsigned int* Xq       = (unsigned int*)((char*)d_ws + 16384);

        // streaming occupancy: 8 blocks/CU for the 25.6 MB read
        absmax_partial_kernel<<<ABS_BLOCKS, 256, 0, stream>>>(X, partials, nx / 4);
        absmax_final_kernel<<<1, 256, 0, stream>>>(partials, scinv, ABS_BLOCKS);

        const int n16 = nx / 16;
        quantize_kernel<<<(n16 + 255) / 256, 256, 0, stream>>>(X, scinv, Xq, n16);

        // 1024-thread blocks, 68 KB LDS -> 2 blocks/CU -> 32 waves/CU (cap).
        const int ngroups = (num_edges + 3) >> 2;
        int grid = 512;
        const int max_grid = (ngroups + 127) / 128;
        if (grid > max_grid) grid = max_grid;
        distmult_i8_lds_kernel<<<grid, 1024, 0, stream>>>(
            Xq, R, scinv, src, tgt, edge_type, out, num_edges, nrel);
    } else {
        int grid = (num_edges + 15) / 16;
        if (grid > 8192) grid = 8192;
        distmult_f32_kernel<<<grid, 256, 0, stream>>>(
            X, R, src, tgt, edge_type, out, num_edges);
    }
}

// Round 13
// 42.191 us; speedup vs baseline: 1.4248x; 1.0668x over previous
//
#include <hip/hip_runtime.h>

#define DIM 64
#define MAX_REL 256
#define RPAD 68              // padded LDS row stride in floats
#define CHUNK_ROWS 32        // rows sharing one quant scale
#define CHUNK_FLOATS 2048    // CHUNK_ROWS * DIM

typedef int          vint4   __attribute__((ext_vector_type(4)));
typedef unsigned int vuint2  __attribute__((ext_vector_type(2)));
typedef float        vfloat4 __attribute__((ext_vector_type(4)));

// ---- Fused prep: one block = one 32-row chunk; absmax + quantize in ONE X read ----
__global__ void __launch_bounds__(256) quantize_chunks_kernel(
        const float* __restrict__ X,      // [nrows, 64] fp32
        unsigned int* __restrict__ Xq,    // [nrows, 16] words (64 B int8 rows)
        float* __restrict__ Sc,           // [nchunks] scale = chunkmax/127
        int nchunks) {
    __shared__ unsigned int red[4];
    const int c = blockIdx.x;
    if (c >= nchunks) return;
    const int t = threadIdx.x;

    // 8 floats/thread, contiguous: thread t covers floats [c*2048 + 8t, +8)
    const float* xp = X + (size_t)c * CHUNK_FLOATS + t * 8;
    const vfloat4 a = *reinterpret_cast<const vfloat4*>(xp);
    const vfloat4 b = *reinterpret_cast<const vfloat4*>(xp + 4);

    unsigned int m = __float_as_uint(a.x) & 0x7fffffffu;
    m = max(m, __float_as_uint(a.y) & 0x7fffffffu);
    m = max(m, __float_as_uint(a.z) & 0x7fffffffu);
    m = max(m, __float_as_uint(a.w) & 0x7fffffffu);
    m = max(m, __float_as_uint(b.x) & 0x7fffffffu);
    m = max(m, __float_as_uint(b.y) & 0x7fffffffu);
    m = max(m, __float_as_uint(b.z) & 0x7fffffffu);
    m = max(m, __float_as_uint(b.w) & 0x7fffffffu);
    for (int off = 32; off > 0; off >>= 1)
        m = max(m, (unsigned int)__shfl_xor((int)m, off, 64));
    if ((t & 63) == 0) red[t >> 6] = m;
    __syncthreads();
    m = max(max(red[0], red[1]), max(red[2], red[3]));

    const float cmax = __uint_as_float(m);
    const float inv  = (cmax > 0.0f) ? (127.0f / cmax) : 0.0f;

    const int q0 = (int)rintf(a.x * inv), q1 = (int)rintf(a.y * inv);
    const int q2 = (int)rintf(a.z * inv), q3 = (int)rintf(a.w * inv);
    const int q4 = (int)rintf(b.x * inv), q5 = (int)rintf(b.y * inv);
    const int q6 = (int)rintf(b.z * inv), q7 = (int)rintf(b.w * inv);
    vuint2 o;
    o.x = (unsigned int)(q0 & 0xff) | ((unsigned int)(q1 & 0xff) << 8) |
          ((unsigned int)(q2 & 0xff) << 16) | ((unsigned int)(q3 & 0xff) << 24);
    o.y = (unsigned int)(q4 & 0xff) | ((unsigned int)(q5 & 0xff) << 8) |
          ((unsigned int)(q6 & 0xff) << 16) | ((unsigned int)(q7 & 0xff) << 24);
    *reinterpret_cast<vuint2*>(Xq + (size_t)c * (CHUNK_FLOATS / 4) + t * 2) = o;

    if (t == 0) Sc[c] = cmax * (1.0f / 127.0f);
}

// ---------------- int8 dot helper ----------------
__device__ __forceinline__ float dot8_i8(const vuint2& s, const vuint2& t,
                                         const vfloat4& ra, const vfloat4& rb) {
    float acc = 0.f;
    int p;
    p = ((int)(s.x << 24) >> 24) * ((int)(t.x << 24) >> 24); acc = fmaf((float)p, ra.x, acc);
    p = ((int)(s.x << 16) >> 24) * ((int)(t.x << 16) >> 24); acc = fmaf((float)p, ra.y, acc);
    p = ((int)(s.x <<  8) >> 24) * ((int)(t.x <<  8) >> 24); acc = fmaf((float)p, ra.z, acc);
    p = ((int)(s.x      ) >> 24) * ((int)(t.x      ) >> 24); acc = fmaf((float)p, ra.w, acc);
    p = ((int)(s.y << 24) >> 24) * ((int)(t.y << 24) >> 24); acc = fmaf((float)p, rb.x, acc);
    p = ((int)(s.y << 16) >> 24) * ((int)(t.y << 16) >> 24); acc = fmaf((float)p, rb.y, acc);
    p = ((int)(s.y <<  8) >> 24) * ((int)(t.y <<  8) >> 24); acc = fmaf((float)p, rb.z, acc);
    p = ((int)(s.y      ) >> 24) * ((int)(t.y      ) >> 24); acc = fmaf((float)p, rb.w, acc);
    return acc;
}

// ---------------- Score kernel: round-11 body + L1-resident chunk scales ----------
// 8 lanes/edge, 4 edges/group, 128 groups per 1024-thread block, 68 KB LDS.
__global__ void __launch_bounds__(1024, 8) distmult_i8_lds_kernel(
        const unsigned int* __restrict__ Xq,  // [nrows, 16] words (64 B rows)
        const float* __restrict__ R,          // [nrel, 64] fp32
        const float* __restrict__ Sc,         // [nchunks] scales (12.5 KB, L1-hot)
        const int*   __restrict__ src,
        const int*   __restrict__ tgt,
        const int*   __restrict__ rel,
        float*       __restrict__ out,
        int num_edges, int nrel) {
    __shared__ float Rs[MAX_REL * RPAD];      // 68 KB

    for (int i = threadIdx.x; i < nrel * 16; i += 1024) {
        const int r = i >> 4, c = (i & 15) * 4;
        *reinterpret_cast<vfloat4*>(&Rs[r * RPAD + c]) =
            *reinterpret_cast<const vfloat4*>(R + (size_t)r * DIM + c);
    }
    __syncthreads();

    const int sub = threadIdx.x & 7;
    const int w0  = sub * 2;
    const int f0  = sub * 8;
    int g = blockIdx.x * 128 + (threadIdx.x >> 3);
    const int gstr = gridDim.x * 128;
    const int ngroups = (num_edges + 3) >> 2;

    for (; g < ngroups; g += gstr) {
        const int e0 = g << 2;
        if (e0 + 3 < num_edges) {
            const vint4 s4 = *reinterpret_cast<const vint4*>(src + e0);
            const vint4 t4 = *reinterpret_cast<const vint4*>(tgt + e0);
            const vint4 r4 = *reinterpret_cast<const vint4*>(rel + e0);

            const vuint2 sv0 = *reinterpret_cast<const vuint2*>(Xq + (size_t)s4.x * 16 + w0);
            const vuint2 sv1 = *reinterpret_cast<const vuint2*>(Xq + (size_t)s4.y * 16 + w0);
            const vuint2 sv2 = *reinterpret_cast<const vuint2*>(Xq + (size_t)s4.z * 16 + w0);
            const vuint2 sv3 = *reinterpret_cast<const vuint2*>(Xq + (size_t)s4.w * 16 + w0);
            const vuint2 tv0 = *reinterpret_cast<const vuint2*>(Xq + (size_t)t4.x * 16 + w0);
            const vuint2 tv1 = *reinterpret_cast<const vuint2*>(Xq + (size_t)t4.y * 16 + w0);
            const vuint2 tv2 = *reinterpret_cast<const vuint2*>(Xq + (size_t)t4.z * 16 + w0);
            const vuint2 tv3 = *reinterpret_cast<const vuint2*>(Xq + (size_t)t4.w * 16 + w0);

            const float* r0 = &Rs[r4.x * RPAD + f0];
            const float* r1 = &Rs[r4.y * RPAD + f0];
            const float* r2 = &Rs[r4.z * RPAD + f0];
            const float* r3 = &Rs[r4.w * RPAD + f0];

            float a0 = dot8_i8(sv0, tv0, *reinterpret_cast<const vfloat4*>(r0),
                                          *reinterpret_cast<const vfloat4*>(r0 + 4));
            float a1 = dot8_i8(sv1, tv1, *reinterpret_cast<const vfloat4*>(r1),
                                          *reinterpret_cast<const vfloat4*>(r1 + 4));
            float a2 = dot8_i8(sv2, tv2, *reinterpret_cast<const vfloat4*>(r2),
                                          *reinterpret_cast<const vfloat4*>(r2 + 4));
            float a3 = dot8_i8(sv3, tv3, *reinterpret_cast<const vfloat4*>(r3),
                                          *reinterpret_cast<const vfloat4*>(r3 + 4));

            a0 += __shfl_xor(a0, 1, 64); a1 += __shfl_xor(a1, 1, 64);
            a2 += __shfl_xor(a2, 1, 64); a3 += __shfl_xor(a3, 1, 64);
            a0 += __shfl_xor(a0, 2, 64); a1 += __shfl_xor(a1, 2, 64);
            a2 += __shfl_xor(a2, 2, 64); a3 += __shfl_xor(a3, 2, 64);
            a0 += __shfl_xor(a0, 4, 64); a1 += __shfl_xor(a1, 4, 64);
            a2 += __shfl_xor(a2, 4, 64); a3 += __shfl_xor(a3, 4, 64);

            if (sub == 0) {
                // exec-masked (8 lanes/wave active): Sc is 12.5 KB -> L1 hits
                const float sc0 = Sc[s4.x >> 5] * Sc[t4.x >> 5];
                const float sc1 = Sc[s4.y >> 5] * Sc[t4.y >> 5];
                const float sc2 = Sc[s4.z >> 5] * Sc[t4.z >> 5];
                const float sc3 = Sc[s4.w >> 5] * Sc[t4.w >> 5];
                vfloat4 o;
                o.x = a0 * sc0; o.y = a1 * sc1; o.z = a2 * sc2; o.w = a3 * sc3;
                *reinterpret_cast<vfloat4*>(out + e0) = o;
            }
        } else {
            for (int e = e0; e < num_edges; ++e) {
                const int s = src[e], t = tgt[e], r = rel[e];
                const vuint2 sv = *reinterpret_cast<const vuint2*>(Xq + (size_t)s * 16 + w0);
                const vuint2 tv = *reinterpret_cast<const vuint2*>(Xq + (size_t)t * 16 + w0);
                const float* rr = &Rs[r * RPAD + f0];
                float acc = dot8_i8(sv, tv, *reinterpret_cast<const vfloat4*>(rr),
                                            *reinterpret_cast<const vfloat4*>(rr + 4));
                acc += __shfl_xor(acc, 1, 64);
                acc += __shfl_xor(acc, 2, 64);
                acc += __shfl_xor(acc, 4, 64);
                if (sub == 0) out[e] = acc * Sc[s >> 5] * Sc[t >> 5];
            }
        }
    }
}

// ---------------- fp32 fallback ----------------
__global__ void __launch_bounds__(256) distmult_f32_kernel(
        const float* __restrict__ X, const float* __restrict__ R,
        const int* __restrict__ src, const int* __restrict__ tgt,
        const int* __restrict__ rel, float* __restrict__ out, int num_edges) {
    const int sub = threadIdx.x & 15;
    int e = blockIdx.x * 16 + (threadIdx.x >> 4);
    const int estr = gridDim.x * 16;
    for (; e < num_edges; e += estr) {
        const int s = src[e], t = tgt[e], r = rel[e];
        const float4 sv = *reinterpret_cast<const float4*>(X + (size_t)s * DIM + sub * 4);
        const float4 tv = *reinterpret_cast<const float4*>(X + (size_t)t * DIM + sub * 4);
        const float4 rv = *reinterpret_cast<const float4*>(R + (size_t)r * DIM + sub * 4);
        float acc = sv.x * rv.x * tv.x + sv.y * rv.y * tv.y
                  + sv.z * rv.z * tv.z + sv.w * rv.w * tv.w;
        acc += __shfl_xor(acc, 1, 64);
        acc += __shfl_xor(acc, 2, 64);
        acc += __shfl_xor(acc, 4, 64);
        acc += __shfl_xor(acc, 8, 64);
        if (sub == 0) out[e] = acc;
    }
}

extern "C" void kernel_launch(void* const* d_in, const int* in_sizes, int n_in,
                              void* d_out, int out_size, void* d_ws, size_t ws_size,
                              hipStream_t stream) {
    const float* X         = (const float*)d_in[0];  // (100000, 64) f32
    const float* R         = (const float*)d_in[1];  // (237, 64) f32
    const int*   edge_list = (const int*)d_in[2];    // (2, NUM_EDGES) i32
    const int*   edge_type = (const int*)d_in[3];    // (1, NUM_EDGES) i32
    float*       out       = (float*)d_out;

    const int num_edges = in_sizes[3];
    const int nx        = in_sizes[0];               // 6.4M floats
    const int nrel      = in_sizes[1] / DIM;         // 237
    const int* src = edge_list;
    const int* tgt = edge_list + num_edges;

    const int nchunks = nx / CHUNK_FLOATS;           // 3125
    // ws layout: [0, nchunks*4) = Sc; [aligned 16K, +nx) = Xq
    const size_t sc_bytes = ((size_t)nchunks * 4 + 16383) & ~(size_t)16383;
    const size_t need = sc_bytes + (size_t)nx;
    if (ws_size >= need && (nx % CHUNK_FLOATS) == 0 && nrel <= MAX_REL) {
        float*        Sc = (float*)d_ws;
        unsigned int* Xq = (unsigned int*)((char*)d_ws + sc_bytes);

        // single fused prep pass: one X read, absmax+quantize per 32-row chunk
        quantize_chunks_kernel<<<nchunks, 256, 0, stream>>>(X, Xq, Sc, nchunks);

        // 1024-thread blocks, 68 KB LDS -> 2 blocks/CU -> 32 waves/CU (cap).
        const int ngroups = (num_edges + 3) >> 2;
        int grid = 512;
        const int max_grid = (ngroups + 127) / 128;
        if (grid > max_grid) grid = max_grid;
        distmult_i8_lds_kernel<<<grid, 1024, 0, stream>>>(
            Xq, R, Sc, src, tgt, edge_type, out, num_edges, nrel);
    } else {
        int grid = (num_edges + 15) / 16;
        if (grid > 8192) grid = 8192;
        distmult_f32_kernel<<<grid, 256, 0, stream>>>(
            X, R, src, tgt, edge_type, out, num_edges);
    }
}